// Round 21
// baseline (130.052 us; speedup 1.0000x reference)
//
#include <hip/hip_runtime.h>
#include <hip/hip_bf16.h>

typedef _Float16 f16x8 __attribute__((ext_vector_type(8)));
typedef _Float16 f16x2 __attribute__((ext_vector_type(2)));
typedef float f32x4 __attribute__((ext_vector_type(4)));
typedef float f32x16 __attribute__((ext_vector_type(16)));
typedef unsigned int u32x2 __attribute__((ext_vector_type(2)));
typedef unsigned int u32x4 __attribute__((ext_vector_type(4)));
typedef unsigned short us8 __attribute__((ext_vector_type(8)));

#define GLDS16(gp, lp)                                                        \
  __builtin_amdgcn_global_load_lds(                                           \
      (const __attribute__((address_space(1))) void*)(gp),                    \
      (__attribute__((address_space(3))) void*)(lp), 16, 0, 0)

#define MEMFENCE asm volatile("" ::: "memory")

__device__ __forceinline__ unsigned short f2h(float f) {
  _Float16 h = (_Float16)f;
  return __builtin_bit_cast(unsigned short, h);
}
__device__ __forceinline__ float h2f(unsigned short u) {
  return (float)__builtin_bit_cast(_Float16, u);
}
__device__ __forceinline__ unsigned int pk2(float a, float b) {
  return __builtin_bit_cast(unsigned int, __builtin_amdgcn_cvt_pkrtz(a, b));
}

// ------------- K1b: weights f32 [256][512] -> f16 transposed [512][256] -----
__global__ __launch_bounds__(256) void k_convert_w(
    const float* __restrict__ Wk, const float* __restrict__ Wv,
    const float* __restrict__ Wq, const float* __restrict__ Wr,
    unsigned short* __restrict__ WT) {
  int o = blockIdx.x * 256 + threadIdx.x;  // 0..524287
  int mat = o >> 17, rem = o & 131071;
  int n = rem >> 8, k = rem & 255;
  const float* W = mat == 0 ? Wk : mat == 1 ? Wv : mat == 2 ? Wq : Wr;
  WT[o] = f2h(W[k * 512 + n]);
}

// ---------------- K2: 4 projection GEMMs, 1-barrier, issues AFTER barrier --
// BM=128, BN=512, BK=32, 8 K-steps. All VMEM issues inside the body (post-
// barrier) so no wave can overwrite a buffer other waves still read (R20
// race). Issue order pinned by empty memory-clobber asm; counted vmcnt.
__global__ __launch_bounds__(1024) void k_gemm(
    const float* __restrict__ k0, const float* __restrict__ v0,
    const float* __restrict__ q0, const unsigned short* __restrict__ WT,
    const float* __restrict__ bk, const float* __restrict__ bv,
    const float* __restrict__ bq, const float* __restrict__ br,
    unsigned short* __restrict__ Kb, unsigned short* __restrict__ Vh,
    unsigned short* __restrict__ Qb, unsigned short* __restrict__ Rh) {
  const float CS = 0.70710678118654752f * 1.44269504088896341f;
  int b = blockIdx.x;                 // 512 blocks
  int mat = b >> 7, my = b & 127;
  const float* A = mat == 0 ? k0 : mat == 1 ? v0 : q0;  // mat 3 shares query0
  const unsigned short* Wm = WT + mat * 131072;
  const float* bias = mat == 0 ? bk : mat == 1 ? bv : mat == 2 ? bq : br;
  unsigned short* C = mat == 0 ? Kb : mat == 1 ? Vh : mat == 2 ? Qb : Rh;
  __shared__ __align__(16) unsigned short As[2][4096];   // [128][32] f16
  __shared__ __align__(16) unsigned short Bs[2][16384];  // [512 n][32 k] f16
  int m0 = my * 128;
  int tid = threadIdx.x, lane = tid & 63, w = tid >> 6;
  int wm = w >> 3, wn = w & 7, q = lane & 15, hi = lane >> 4;
  f32x4 acc[4][4];
#pragma unroll
  for (int i = 0; i < 4; ++i)
#pragma unroll
    for (int j = 0; j < 4; ++j) acc[i][j] = f32x4{0.f, 0.f, 0.f, 0.f};

  // bias first (oldest in vmcnt queue -> drained by prologue's vmcnt(1))
  float bsv[4];
#pragma unroll
  for (int j = 0; j < 4; ++j) bsv[j] = bias[wn * 64 + j * 16 + q];
  MEMFENCE;

  const float* gA = A + (m0 + (tid >> 3)) * 256 + (tid & 7) * 4;
  const unsigned short* gB = Wm + (tid >> 2) * 256 + (tid & 3) * 8;

  // ---- prologue: B(0)->LDS[0]; then A(0),A(1)->regs (order pinned) ----
  GLDS16(gB, &Bs[0][tid * 8]);
  GLDS16(gB + 65536, &Bs[0][8192 + tid * 8]);
  MEMFENCE;
  float4 tmp = *(const float4*)gA;       // A0
  float4 arF[2];
  arF[1] = *(const float4*)(gA + 32);    // A1
  // outstanding: [bias*4, B0a, B0b, A0, A1] -> vmcnt(1) leaves A1
  asm volatile("s_waitcnt vmcnt(1)" ::: "memory");
  *(u32x2*)&As[0][tid * 4] = u32x2{pk2(tmp.x, tmp.y), pk2(tmp.z, tmp.w)};

#pragma unroll
  for (int kt = 0; kt < 8; ++kt) {
    int cur = kt & 1, nxt = cur ^ 1;
    // top: B(kt) must be in LDS; A(kt+1) may stay in flight
    if (kt == 7) asm volatile("s_waitcnt vmcnt(0)" ::: "memory");
    else asm volatile("s_waitcnt vmcnt(1)" ::: "memory");
    asm volatile("s_waitcnt lgkmcnt(0)" ::: "memory");  // own writes/reads done
    __builtin_amdgcn_s_barrier();
    __builtin_amdgcn_sched_barrier(0);

    // body: issue next tiles (AFTER the barrier -> no cross-wave WAR)
    if (kt < 7) {
      GLDS16(gB + (kt + 1) * 32, &Bs[nxt][tid * 8]);
      GLDS16(gB + (kt + 1) * 32 + 65536, &Bs[nxt][8192 + tid * 8]);
    }
    MEMFENCE;  // pin: GLDS B(kt+1) before A(kt+2) in the vmcnt queue
    if (kt < 6) arF[cur] = *(const float4*)(gA + (kt + 2) * 32);

    f16x8 af[4], bf[4];
#pragma unroll
    for (int i = 0; i < 4; ++i)
      af[i] = *(const f16x8*)&As[cur][(wm * 64 + i * 16 + q) * 32 + hi * 8];
#pragma unroll
    for (int j = 0; j < 4; ++j)
      bf[j] = *(const f16x8*)&Bs[cur][(wn * 64 + j * 16 + q) * 32 + hi * 8];
#pragma unroll
    for (int i = 0; i < 4; ++i)
#pragma unroll
      for (int j = 0; j < 4; ++j)
        acc[i][j] = __builtin_amdgcn_mfma_f32_16x16x32_f16(af[i], bf[j], acc[i][j], 0, 0, 0);

    if (kt < 7) {
      // drain A(kt+1): newer in queue are [B(kt+1)a, B(kt+1)b, A(kt+2)]
      if (kt < 6) asm volatile("s_waitcnt vmcnt(3)" ::: "memory");
      else asm volatile("s_waitcnt vmcnt(2)" ::: "memory");
      *(u32x2*)&As[nxt][tid * 4] =
          u32x2{pk2(arF[nxt].x, arF[nxt].y), pk2(arF[nxt].z, arF[nxt].w)};
    }
  }

  float scale = (mat == 2) ? CS : 1.0f;
#pragma unroll
  for (int j = 0; j < 4; ++j) {
    int col = wn * 64 + j * 16 + q;
    float bs = bsv[j];
#pragma unroll
    for (int i = 0; i < 4; ++i) {
      int rb = m0 + wm * 64 + i * 16 + 4 * hi;
#pragma unroll
      for (int r = 0; r < 4; ++r) {
        float v = (acc[i][j][r] + bs) * scale;
        C[(rb + r) * 512 + col] = f2h(v);
      }
    }
  }
}

// -------- K2b: V transpose per group: Vt[g][d][s] = Vh(flat)[g][s][d] -------
__global__ __launch_bounds__(256) void k_vt(
    const unsigned short* __restrict__ Vh, unsigned short* __restrict__ Vt) {
  int t0 = blockIdx.x * 256 + threadIdx.x;  // 0..524287
#pragma unroll
  for (int it = 0; it < 2; ++it) {
    int c = t0 + it * 524288;
    int s8 = c & 127, d = (c >> 7) & 31, g = c >> 12;
    const unsigned short* src = Vh + g * 32768 + s8 * 256 + d;
    us8 v;
#pragma unroll
    for (int i = 0; i < 8; ++i) v[i] = src[i * 32];
    *(us8*)&Vt[g * 32768 + d * 1024 + s8 * 8] = v;
  }
}

// ---------------- K3: attention (32x32 MFMA, T12, 1-deep st pipeline) ------
// (R16/R18-verified best: 57.7us; launched <<<256,1024>>>.)
#define QK2(dst, kk0, kk1, qtl)                                               \
  dst = __builtin_amdgcn_mfma_f32_32x32x16_f16(kk0, qf[qtl][0], neg24, 0, 0, 0); \
  dst = __builtin_amdgcn_mfma_f32_32x32x16_f16(kk1, qf[qtl][1], dst, 0, 0, 0);

#define LOADKF(kv, blk, d0, d1)                                               \
  d0 = *(const f16x8*)(Ks + (kbase ^ 0) + (kv) * 4096 + (blk) * 2048);        \
  d1 = *(const f16x8*)(Ks + (kbase ^ 32) + (kv) * 4096 + (blk) * 2048);

#define LOADVF(kv, blk, d0, d1)                                               \
  d0 = *(const f16x8*)(Vs + ((vbase ^ ((2 * (blk)) << 5)) + (kv) * 128));     \
  d1 = *(const f16x8*)(Vs + ((vbase ^ ((2 * (blk) + 1) << 5)) + (kv) * 128));

#define PROC(st, qtl, vv0, vv1)                                               \
  {                                                                           \
    unsigned int w_[8];                                                       \
    _Pragma("unroll") for (int m = 0; m < 8; ++m) {                           \
      float p0_ = __builtin_amdgcn_exp2f(st[2 * m]);                          \
      float p1_ = __builtin_amdgcn_exp2f(st[2 * m + 1]);                      \
      w_[m] = pk2(p0_, p1_);                                                  \
    }                                                                         \
    _Pragma("unroll") for (int m = 0; m < 8; ++m)                             \
      lacc[qtl] = __builtin_amdgcn_fdot2(__builtin_bit_cast(f16x2, w_[m]),    \
                                         ones2, lacc[qtl], false);            \
    unsigned int a0_ = w_[0], a2_ = w_[2], a1_ = w_[1], a3_ = w_[3];          \
    unsigned int b0_ = w_[4], b2_ = w_[6], b1_ = w_[5], b3_ = w_[7];          \
    asm("v_permlane32_swap_b32 %0, %1" : "+v"(a0_), "+v"(a2_));               \
    asm("v_permlane32_swap_b32 %0, %1" : "+v"(a1_), "+v"(a3_));               \
    asm("v_permlane32_swap_b32 %0, %1" : "+v"(b0_), "+v"(b2_));               \
    asm("v_permlane32_swap_b32 %0, %1" : "+v"(b1_), "+v"(b3_));               \
    f16x8 pb0_ = __builtin_bit_cast(f16x8, (u32x4){a0_, a1_, a2_, a3_});      \
    f16x8 pb1_ = __builtin_bit_cast(f16x8, (u32x4){b0_, b1_, b2_, b3_});      \
    o[qtl] = __builtin_amdgcn_mfma_f32_32x32x16_f16(vv0, pb0_, o[qtl], 0, 0, 0); \
    o[qtl] = __builtin_amdgcn_mfma_f32_32x32x16_f16(vv1, pb1_, o[qtl], 0, 0, 0); \
  }

__global__ __launch_bounds__(1024) void k_attn(
    const unsigned short* __restrict__ Kb, const unsigned short* __restrict__ Vt,
    const unsigned short* __restrict__ Qb, const unsigned short* __restrict__ Rh,
    float* __restrict__ out) {
  __shared__ __align__(16) char Ks[65536];  // [1024 s][32 d] swizzled
  __shared__ __align__(16) char Vs[65536];  // [32 d][1024 s] swizzled

  int p = blockIdx.x;                 // 256 blocks, 1 per group
  int g = (p & 7) * 32 + (p >> 3);    // XCD-bijective
  int tid = threadIdx.x, lane = tid & 63, wid = tid >> 6;
  int q = lane & 31, h2 = lane >> 5;

  const char* Ksrc = (const char*)Kb + (size_t)g * 65536;
  const char* Vsrc = (const char*)Vt + (size_t)g * 65536;
#pragma unroll
  for (int r = 0; r < 4; ++r) {
    int d = tid * 16 + r * 16384;
    GLDS16(Ksrc + (d ^ (((d >> 7) & 7) << 4)), Ks + d);
    GLDS16(Vsrc + (d ^ (((d >> 11) & 7) << 4)), Vs + d);
  }

  const unsigned short* Qg = Qb + g * 32768 + wid * 2048;
  f16x8 qf[2][2];
#pragma unroll
  for (int qt = 0; qt < 2; ++qt)
#pragma unroll
    for (int kh = 0; kh < 2; ++kh)
      qf[qt][kh] = *(const f16x8*)&Qg[(qt * 32 + q) * 32 + kh * 16 + h2 * 8];

  int kbase = (q * 64 + h2 * 16) ^ (((q >> 1) & 7) << 4);
  int vbase = (q * 2048 + h2 * 16) ^ ((q & 7) << 4);

  const f16x2 ones2 = {(_Float16)1.0f, (_Float16)1.0f};
  f32x16 o[2];
#pragma unroll
  for (int i = 0; i < 16; ++i) { o[0][i] = 0.f; o[1][i] = 0.f; }
  float lacc[2] = {0.f, 0.f};
  f32x16 neg24;
#pragma unroll
  for (int i = 0; i < 16; ++i) neg24[i] = -24.f;

  __syncthreads();  // staging complete

  f16x8 k0A, k1A, v0A, v1A, k0B, k1B, v0B, v1B;
  f32x16 stA, s1, s2, s3;
  LOADKF(0, 0, k0A, k1A);
  LOADVF(0, 0, v0A, v1A);
  QK2(stA, k0A, k1A, 0);

  for (int kv = 0; kv < 16; ++kv) {
    QK2(s1, k0A, k1A, 1);
    PROC(stA, 0, v0A, v1A);
    LOADKF(kv, 1, k0B, k1B);
    LOADVF(kv, 1, v0B, v1B);
    QK2(s2, k0B, k1B, 0);
    PROC(s1, 1, v0A, v1A);
    QK2(s3, k0B, k1B, 1);
    PROC(s2, 0, v0B, v1B);
    if (kv < 15) {
      LOADKF(kv + 1, 0, k0A, k1A);
      LOADVF(kv + 1, 0, v0A, v1A);
      QK2(stA, k0A, k1A, 0);
    }
    PROC(s3, 1, v0B, v1B);
  }

#pragma unroll
  for (int qt = 0; qt < 2; ++qt)
    lacc[qt] += __shfl_xor(lacc[qt], 32, 64);

#pragma unroll
  for (int qt = 0; qt < 2; ++qt) {
    float iv = 1.0f / lacc[qt];
    int rowoff = g * 32768 + (wid * 64 + qt * 32 + q) * 32;
#pragma unroll
    for (int rg = 0; rg < 4; ++rg) {
      int off = rowoff + rg * 8 + h2 * 4;   // d = (r&3) + 8*rg + 4*h2
      ushort4 rr = *(const ushort4*)&Rh[off];
      float4 ov;
      ov.x = fmaxf(h2f(rr.x) + o[qt][4 * rg + 0] * iv, 0.f);
      ov.y = fmaxf(h2f(rr.y) + o[qt][4 * rg + 1] * iv, 0.f);
      ov.z = fmaxf(h2f(rr.z) + o[qt][4 * rg + 2] * iv, 0.f);
      ov.w = fmaxf(h2f(rr.w) + o[qt][4 * rg + 3] * iv, 0.f);
      *(float4*)&out[off] = ov;
    }
  }
}

extern "C" void kernel_launch(void* const* d_in, const int* in_sizes, int n_in,
                              void* d_out, int out_size, void* d_ws, size_t ws_size,
                              hipStream_t stream) {
  const float* key0 = (const float*)d_in[0];
  const float* value0 = (const float*)d_in[1];
  const float* query0 = (const float*)d_in[2];
  const float* Wk = (const float*)d_in[3];
  const float* bk = (const float*)d_in[4];
  const float* Wv = (const float*)d_in[5];
  const float* bv = (const float*)d_in[6];
  const float* Wq = (const float*)d_in[7];
  const float* bq = (const float*)d_in[8];
  const float* Wr = (const float*)d_in[9];
  const float* br = (const float*)d_in[10];
  float* out = (float*)d_out;
  char* ws = (char*)d_ws;
  unsigned short* Kb = (unsigned short*)(ws);              // 16 MB f16 [16384,512]
  unsigned short* Vt = (unsigned short*)(ws + 16777216);   // 16 MB f16 [256][32][1024]
  unsigned short* Qb = (unsigned short*)(ws + 33554432);   // 16 MB f16 (pre-scaled)
  unsigned short* Rh = (unsigned short*)(ws + 50331648);   // 16 MB f16 [16384,512]
  unsigned short* WT = (unsigned short*)(ws + 92274688);   // 1 MB f16 [4][512][256]
  unsigned short* Vh = (unsigned short*)(ws + 93323264);   // 16 MB f16 [16384,512]

  k_convert_w<<<dim3(2048), dim3(256), 0, stream>>>(Wk, Wv, Wq, Wr, WT);
  k_gemm<<<dim3(512), dim3(1024), 0, stream>>>(key0, value0, query0, WT,
                                               bk, bv, bq, br, Kb, Vh, Qb, Rh);
  k_vt<<<dim3(2048), dim3(256), 0, stream>>>(Vh, Vt);
  k_attn<<<dim3(256), dim3(1024), 0, stream>>>(Kb, Vt, Qb, Rh, out);
}

// Round 23
// 96.557 us; speedup vs baseline: 1.3469x; 1.3469x over previous
//
#include <hip/hip_runtime.h>
#include <hip/hip_bf16.h>

typedef _Float16 f16x8 __attribute__((ext_vector_type(8)));
typedef _Float16 f16x2 __attribute__((ext_vector_type(2)));
typedef float f32x4 __attribute__((ext_vector_type(4)));
typedef float f32x16 __attribute__((ext_vector_type(16)));
typedef unsigned int u32x2 __attribute__((ext_vector_type(2)));
typedef unsigned int u32x4 __attribute__((ext_vector_type(4)));
typedef unsigned short us8 __attribute__((ext_vector_type(8)));

#define GLDS16(gp, lp)                                                        \
  __builtin_amdgcn_global_load_lds(                                           \
      (const __attribute__((address_space(1))) void*)(gp),                    \
      (__attribute__((address_space(3))) void*)(lp), 16, 0, 0)

__device__ __forceinline__ unsigned short f2h(float f) {
  _Float16 h = (_Float16)f;
  return __builtin_bit_cast(unsigned short, h);
}
__device__ __forceinline__ float h2f(unsigned short u) {
  return (float)__builtin_bit_cast(_Float16, u);
}
__device__ __forceinline__ unsigned int pk2(float a, float b) {
  return __builtin_bit_cast(unsigned int, __builtin_amdgcn_cvt_pkrtz(a, b));
}

// ------------- K1b: weights f32 [256][512] -> f16 transposed [512][256] -----
__global__ __launch_bounds__(256) void k_convert_w(
    const float* __restrict__ Wk, const float* __restrict__ Wv,
    const float* __restrict__ Wq, const float* __restrict__ Wr,
    unsigned short* __restrict__ WT) {
  int o = blockIdx.x * 256 + threadIdx.x;  // 0..524287
  int mat = o >> 17, rem = o & 131071;
  int n = rem >> 8, k = rem & 255;
  const float* W = mat == 0 ? Wk : mat == 1 ? Wv : mat == 2 ? Wq : Wr;
  WT[o] = f2h(W[k * 512 + n]);
}

// ---------------- K2: 4 projection GEMMs, counted-vmcnt (R18-verified) -----
// BM=128, BN=512, BK=32; issue-before-wait, 2 barriers/step, counted vmcnt.
__global__ __launch_bounds__(1024) void k_gemm(
    const float* __restrict__ k0, const float* __restrict__ v0,
    const float* __restrict__ q0, const unsigned short* __restrict__ WT,
    const float* __restrict__ bk, const float* __restrict__ bv,
    const float* __restrict__ bq, const float* __restrict__ br,
    unsigned short* __restrict__ Kb, unsigned short* __restrict__ Vh,
    unsigned short* __restrict__ Qb, unsigned short* __restrict__ Rh) {
  const float CS = 0.70710678118654752f * 1.44269504088896341f;
  int b = blockIdx.x;                 // 512 blocks
  int mat = b >> 7, my = b & 127;
  const float* A = mat == 0 ? k0 : mat == 1 ? v0 : q0;  // mat 3 shares query0
  const unsigned short* Wm = WT + mat * 131072;
  const float* bias = mat == 0 ? bk : mat == 1 ? bv : mat == 2 ? bq : br;
  unsigned short* C = mat == 0 ? Kb : mat == 1 ? Vh : mat == 2 ? Qb : Rh;
  __shared__ __align__(16) unsigned short As[2][4096];   // [128][32] f16
  __shared__ __align__(16) unsigned short Bs[2][16384];  // [512 n][32 k] f16
  int m0 = my * 128;
  int tid = threadIdx.x, lane = tid & 63, w = tid >> 6;
  int wm = w >> 3, wn = w & 7, q = lane & 15, hi = lane >> 4;
  f32x4 acc[4][4];
#pragma unroll
  for (int i = 0; i < 4; ++i)
#pragma unroll
    for (int j = 0; j < 4; ++j) acc[i][j] = f32x4{0.f, 0.f, 0.f, 0.f};

  float bsv[4];
#pragma unroll
  for (int j = 0; j < 4; ++j) bsv[j] = bias[wn * 64 + j * 16 + q];

  const float* gA = A + (m0 + (tid >> 3)) * 256 + (tid & 7) * 4;
  const unsigned short* gB = Wm + (tid >> 2) * 256 + (tid & 3) * 8;

  float4 arF[2];
  arF[0] = *(const float4*)gA;
  arF[1] = *(const float4*)(gA + 32);
  GLDS16(gB, &Bs[0][tid * 8]);
  GLDS16(gB + 65536, &Bs[0][8192 + tid * 8]);
  asm volatile("s_waitcnt vmcnt(3)" ::: "memory");
  *(u32x2*)&As[0][tid * 4] =
      u32x2{pk2(arF[0].x, arF[0].y), pk2(arF[0].z, arF[0].w)};
  asm volatile("s_waitcnt lgkmcnt(0)" ::: "memory");
  __builtin_amdgcn_s_barrier();
  __builtin_amdgcn_sched_barrier(0);

#pragma unroll
  for (int kt = 0; kt < 8; ++kt) {
    int cur = kt & 1, nxt = cur ^ 1;
    if (kt < 6) arF[cur] = *(const float4*)(gA + (kt + 2) * 32);
    if (kt < 7) {
      GLDS16(gB + (kt + 1) * 32, &Bs[nxt][tid * 8]);
      GLDS16(gB + (kt + 1) * 32 + 65536, &Bs[nxt][8192 + tid * 8]);
    }
    if (kt < 6) asm volatile("s_waitcnt vmcnt(3)" ::: "memory");
    else if (kt == 6) asm volatile("s_waitcnt vmcnt(2)" ::: "memory");
    else asm volatile("s_waitcnt vmcnt(0)" ::: "memory");
    __builtin_amdgcn_s_barrier();
    __builtin_amdgcn_sched_barrier(0);

    f16x8 af[4], bf[4];
#pragma unroll
    for (int i = 0; i < 4; ++i)
      af[i] = *(const f16x8*)&As[cur][(wm * 64 + i * 16 + q) * 32 + hi * 8];
#pragma unroll
    for (int j = 0; j < 4; ++j)
      bf[j] = *(const f16x8*)&Bs[cur][(wn * 64 + j * 16 + q) * 32 + hi * 8];
#pragma unroll
    for (int i = 0; i < 4; ++i)
#pragma unroll
      for (int j = 0; j < 4; ++j)
        acc[i][j] = __builtin_amdgcn_mfma_f32_16x16x32_f16(af[i], bf[j], acc[i][j], 0, 0, 0);

    if (kt < 7) {
      *(u32x2*)&As[nxt][tid * 4] =
          u32x2{pk2(arF[nxt].x, arF[nxt].y), pk2(arF[nxt].z, arF[nxt].w)};
    }
    asm volatile("s_waitcnt lgkmcnt(0)" ::: "memory");
    __builtin_amdgcn_s_barrier();
    __builtin_amdgcn_sched_barrier(0);
  }

  float scale = (mat == 2) ? CS : 1.0f;
#pragma unroll
  for (int j = 0; j < 4; ++j) {
    int col = wn * 64 + j * 16 + q;
    float bs = bsv[j];
#pragma unroll
    for (int i = 0; i < 4; ++i) {
      int rb = m0 + wm * 64 + i * 16 + 4 * hi;
#pragma unroll
      for (int r = 0; r < 4; ++r) {
        float v = (acc[i][j][r] + bs) * scale;
        C[(rb + r) * 512 + col] = f2h(v);
      }
    }
  }
}

// ---------------- K3: attention (32x32 MFMA, T12, 1-deep st pipeline) ------
// V transposed during staging with the k_vt-PROVEN gather shape: thread owns
// a (d, s8) tile, gathers 8 s-values at fixed d (strided 2B reads, same as
// k_vt), writes ONE contiguous ds_write_b128 at the swizzled row offset.
// Container bits provably identical to the R16-verified GLDS-staged Vs.
#define QK2(dst, kk0, kk1, qtl)                                               \
  dst = __builtin_amdgcn_mfma_f32_32x32x16_f16(kk0, qf[qtl][0], neg24, 0, 0, 0); \
  dst = __builtin_amdgcn_mfma_f32_32x32x16_f16(kk1, qf[qtl][1], dst, 0, 0, 0);

#define LOADKF(kv, blk, d0, d1)                                               \
  d0 = *(const f16x8*)(Ks + (kbase ^ 0) + (kv) * 4096 + (blk) * 2048);        \
  d1 = *(const f16x8*)(Ks + (kbase ^ 32) + (kv) * 4096 + (blk) * 2048);

#define LOADVF(kv, blk, d0, d1)                                               \
  d0 = *(const f16x8*)(Vs + ((vbase ^ ((2 * (blk)) << 5)) + (kv) * 128));     \
  d1 = *(const f16x8*)(Vs + ((vbase ^ ((2 * (blk) + 1) << 5)) + (kv) * 128));

#define PROC(st, qtl, vv0, vv1)                                               \
  {                                                                           \
    unsigned int w_[8];                                                       \
    _Pragma("unroll") for (int m = 0; m < 8; ++m) {                           \
      float p0_ = __builtin_amdgcn_exp2f(st[2 * m]);                          \
      float p1_ = __builtin_amdgcn_exp2f(st[2 * m + 1]);                      \
      w_[m] = pk2(p0_, p1_);                                                  \
    }                                                                         \
    _Pragma("unroll") for (int m = 0; m < 8; ++m)                             \
      lacc[qtl] = __builtin_amdgcn_fdot2(__builtin_bit_cast(f16x2, w_[m]),    \
                                         ones2, lacc[qtl], false);            \
    unsigned int a0_ = w_[0], a2_ = w_[2], a1_ = w_[1], a3_ = w_[3];          \
    unsigned int b0_ = w_[4], b2_ = w_[6], b1_ = w_[5], b3_ = w_[7];          \
    asm("v_permlane32_swap_b32 %0, %1" : "+v"(a0_), "+v"(a2_));               \
    asm("v_permlane32_swap_b32 %0, %1" : "+v"(a1_), "+v"(a3_));               \
    asm("v_permlane32_swap_b32 %0, %1" : "+v"(b0_), "+v"(b2_));               \
    asm("v_permlane32_swap_b32 %0, %1" : "+v"(b1_), "+v"(b3_));               \
    f16x8 pb0_ = __builtin_bit_cast(f16x8, (u32x4){a0_, a1_, a2_, a3_});      \
    f16x8 pb1_ = __builtin_bit_cast(f16x8, (u32x4){b0_, b1_, b2_, b3_});      \
    o[qtl] = __builtin_amdgcn_mfma_f32_32x32x16_f16(vv0, pb0_, o[qtl], 0, 0, 0); \
    o[qtl] = __builtin_amdgcn_mfma_f32_32x32x16_f16(vv1, pb1_, o[qtl], 0, 0, 0); \
  }

__global__ __launch_bounds__(1024) void k_attn(
    const unsigned short* __restrict__ Kb, const unsigned short* __restrict__ Vh,
    const unsigned short* __restrict__ Qb, const unsigned short* __restrict__ Rh,
    float* __restrict__ out) {
  __shared__ __align__(16) char Ks[65536];  // [1024 s][32 d] swizzled
  __shared__ __align__(16) char Vs[65536];  // [32 d][1024 s] swizzled

  int p = blockIdx.x;                 // 256 blocks, 1 per group
  int g = (p & 7) * 32 + (p >> 3);    // XCD-bijective
  int tid = threadIdx.x, lane = tid & 63, wid = tid >> 6;
  int q = lane & 31, h2 = lane >> 5;

  // ---- K: GLDS with inverse-swizzled source (unchanged, verified) ----
  const char* Ksrc = (const char*)Kb + (size_t)g * 65536;
#pragma unroll
  for (int r = 0; r < 4; ++r) {
    int dk = tid * 16 + r * 16384;
    GLDS16(Ksrc + (dk ^ (((dk >> 7) & 7) << 4)), Ks + dk);
  }

  // ---- V: k_vt-shape transpose from Vh[s][d] into swizzled Vs[d][s] ----
  {
    const unsigned short* VhG = Vh + g * 32768;
    int d = tid & 31, s8b = tid >> 5;   // 32 d x 32 s8b; 4 iters -> s8 in [0,128)
#pragma unroll
    for (int it = 0; it < 4; ++it) {
      int s8 = s8b + it * 32;
      us8 v;
#pragma unroll
      for (int i = 0; i < 8; ++i) v[i] = VhG[(s8 * 8 + i) * 32 + d];
      *(us8*)(Vs + ((d * 2048 + s8 * 16) ^ ((d & 7) << 4))) = v;
    }
  }

  const unsigned short* Qg = Qb + g * 32768 + wid * 2048;
  f16x8 qf[2][2];
#pragma unroll
  for (int qt = 0; qt < 2; ++qt)
#pragma unroll
    for (int kh = 0; kh < 2; ++kh)
      qf[qt][kh] = *(const f16x8*)&Qg[(qt * 32 + q) * 32 + kh * 16 + h2 * 8];

  int kbase = (q * 64 + h2 * 16) ^ (((q >> 1) & 7) << 4);
  int vbase = (q * 2048 + h2 * 16) ^ ((q & 7) << 4);

  const f16x2 ones2 = {(_Float16)1.0f, (_Float16)1.0f};
  f32x16 o[2];
#pragma unroll
  for (int i = 0; i < 16; ++i) { o[0][i] = 0.f; o[1][i] = 0.f; }
  float lacc[2] = {0.f, 0.f};
  f32x16 neg24;
#pragma unroll
  for (int i = 0; i < 16; ++i) neg24[i] = -24.f;

  __syncthreads();  // drains GLDS (vmcnt) + ds_writes (lgkm) for all waves

  f16x8 k0A, k1A, v0A, v1A, k0B, k1B, v0B, v1B;
  f32x16 stA, s1, s2, s3;
  LOADKF(0, 0, k0A, k1A);
  LOADVF(0, 0, v0A, v1A);
  QK2(stA, k0A, k1A, 0);

  for (int kv = 0; kv < 16; ++kv) {
    QK2(s1, k0A, k1A, 1);
    PROC(stA, 0, v0A, v1A);
    LOADKF(kv, 1, k0B, k1B);
    LOADVF(kv, 1, v0B, v1B);
    QK2(s2, k0B, k1B, 0);
    PROC(s1, 1, v0A, v1A);
    QK2(s3, k0B, k1B, 1);
    PROC(s2, 0, v0B, v1B);
    if (kv < 15) {
      LOADKF(kv + 1, 0, k0A, k1A);
      LOADVF(kv + 1, 0, v0A, v1A);
      QK2(stA, k0A, k1A, 0);
    }
    PROC(s3, 1, v0B, v1B);
  }

#pragma unroll
  for (int qt = 0; qt < 2; ++qt)
    lacc[qt] += __shfl_xor(lacc[qt], 32, 64);

#pragma unroll
  for (int qt = 0; qt < 2; ++qt) {
    float iv = 1.0f / lacc[qt];
    int rowoff = g * 32768 + (wid * 64 + qt * 32 + q) * 32;
#pragma unroll
    for (int rg = 0; rg < 4; ++rg) {
      int off = rowoff + rg * 8 + h2 * 4;   // d = (r&3) + 8*rg + 4*h2
      ushort4 rr = *(const ushort4*)&Rh[off];
      float4 ov;
      ov.x = fmaxf(h2f(rr.x) + o[qt][4 * rg + 0] * iv, 0.f);
      ov.y = fmaxf(h2f(rr.y) + o[qt][4 * rg + 1] * iv, 0.f);
      ov.z = fmaxf(h2f(rr.z) + o[qt][4 * rg + 2] * iv, 0.f);
      ov.w = fmaxf(h2f(rr.w) + o[qt][4 * rg + 3] * iv, 0.f);
      *(float4*)&out[off] = ov;
    }
  }
}

extern "C" void kernel_launch(void* const* d_in, const int* in_sizes, int n_in,
                              void* d_out, int out_size, void* d_ws, size_t ws_size,
                              hipStream_t stream) {
  const float* key0 = (const float*)d_in[0];
  const float* value0 = (const float*)d_in[1];
  const float* query0 = (const float*)d_in[2];
  const float* Wk = (const float*)d_in[3];
  const float* bk = (const float*)d_in[4];
  const float* Wv = (const float*)d_in[5];
  const float* bv = (const float*)d_in[6];
  const float* Wq = (const float*)d_in[7];
  const float* bq = (const float*)d_in[8];
  const float* Wr = (const float*)d_in[9];
  const float* br = (const float*)d_in[10];
  float* out = (float*)d_out;
  char* ws = (char*)d_ws;
  unsigned short* Kb = (unsigned short*)(ws);              // 16 MB f16 [16384,512]
  unsigned short* Vh = (unsigned short*)(ws + 16777216);   // 16 MB f16 [16384,512]
  unsigned short* Qb = (unsigned short*)(ws + 33554432);   // 16 MB f16 (pre-scaled)
  unsigned short* Rh = (unsigned short*)(ws + 50331648);   // 16 MB f16 [16384,512]
  unsigned short* WT = (unsigned short*)(ws + 92274688);   // 1 MB f16 [4][512][256]

  k_convert_w<<<dim3(2048), dim3(256), 0, stream>>>(Wk, Wv, Wq, Wr, WT);
  k_gemm<<<dim3(512), dim3(1024), 0, stream>>>(key0, value0, query0, WT,
                                               bk, bv, bq, br, Kb, Vh, Qb, Rh);
  k_attn<<<dim3(256), dim3(1024), 0, stream>>>(Kb, Vh, Qb, Rh, out);
}